// Round 9
// baseline (458.769 us; speedup 1.0000x reference)
//
#include <hip/hip_runtime.h>

// ---------------------------------------------------------------------------
// LinearAttention forward. Inputs/outputs FLOAT32; internal compute bf16 MFMA
// with fp32 accumulation. B=2, T=8192 (BT=16384), HID=1024, H=8, DK=DV=128.
// ws layout (MB): [0,32) Q (O in-place) | [32,64) Kf | [64,96) VT |
//   [96,160) KV (Xb bf16 overlays [96,128) until QKV GEMM done) |
//   [160,168) Wq/Wk/Wv/Wo bf16 | [168,+128KB) fm weights bf16
// NOTE (R4): no fm fusion into qkv epilogue (+34.8KB LDS/+128 VGPR -> 291us).
// NOTE (R6/R7): 32x32x16 MFMA on this BK=32 staging layout has 3x LDS bank
//   conflicts that an XOR read swizzle did NOT fix -> 153-158us vs 141us.
//   16x16x32 fragment geometry (row=lq, col=quad*16B) is bank-optimal here.
// R9: attn LDS 63.5KB -> 53KB (3 blocks/CU); cumsum uint2-vectorized;
//   all f32->bf16 conversions in one launch.
// ---------------------------------------------------------------------------

typedef __bf16 bf16x8 __attribute__((ext_vector_type(8)));
typedef float  f32x4  __attribute__((ext_vector_type(4)));

__device__ __forceinline__ float bf2f(unsigned int u) {
  union { unsigned int i; float f; } v; v.i = u << 16; return v.f;
}
__device__ __forceinline__ unsigned short f2bf(float f) {
  union { float f; unsigned int i; } v; v.f = f;
  return (unsigned short)((v.i + 0x8000u) >> 16);  // round-half-up
}
__device__ __forceinline__ unsigned int pk2(float a, float b) {
  union { float f; unsigned int i; } x, y; x.f = a; y.f = b;
  return ((x.i + 0x8000u) >> 16) | ((y.i + 0x8000u) & 0xFFFF0000u);
}
__device__ __forceinline__ f32x4 mfma16(bf16x8 a, bf16x8 b, f32x4 c) {
  return __builtin_amdgcn_mfma_f32_16x16x32_bf16(a, b, c, 0, 0, 0);
}
// Async global->LDS, 16B per lane. LDS dest = wave-uniform base + lane*16.
__device__ __forceinline__ void gl_lds16(const unsigned short* g, unsigned short* l) {
  __builtin_amdgcn_global_load_lds((const __attribute__((address_space(1))) void*)g,
                                   (__attribute__((address_space(3))) void*)l, 16, 0, 0);
}

// ---------------------------------------------------------------------------
// One-shot f32 -> bf16 conversion for all 9 tensors (flat float4 index space):
// [0, 4194304) X | [.., +1048576) Wq/Wk/Wv/Wo | [.., +16384) fm weights.
// Grid 20544 x 256 covers 5,259,264 float4s exactly.
// ---------------------------------------------------------------------------
__global__ void __launch_bounds__(256)
cvt_all(const float* __restrict__ X, const float* __restrict__ Wq,
        const float* __restrict__ Wk, const float* __restrict__ Wv,
        const float* __restrict__ Wo,
        const float* __restrict__ g1, const float* __restrict__ g2,
        const float* __restrict__ g3, const float* __restrict__ g4,
        unsigned short* __restrict__ Xb, unsigned short* __restrict__ Wqb,
        unsigned short* __restrict__ Wkb, unsigned short* __restrict__ Wvb,
        unsigned short* __restrict__ Wob,
        unsigned short* __restrict__ g1b, unsigned short* __restrict__ g2b,
        unsigned short* __restrict__ g3b, unsigned short* __restrict__ g4b) {
  const unsigned int i = blockIdx.x * 256 + threadIdx.x;
  const float* s; unsigned short* d; unsigned int off;
  if (i < 4194304u) {
    s = X; d = Xb; off = i;
  } else {
    const unsigned int j = i - 4194304u;
    if (j < 1048576u) {
      const unsigned int t = j >> 18; off = j & 262143u;
      s = (t == 0) ? Wq : (t == 1) ? Wk : (t == 2) ? Wv : Wo;
      d = (t == 0) ? Wqb : (t == 1) ? Wkb : (t == 2) ? Wvb : Wob;
    } else {
      const unsigned int j2 = j - 1048576u;
      const unsigned int t = j2 >> 12; off = j2 & 4095u;
      s = (t == 0) ? g1 : (t == 1) ? g2 : (t == 2) ? g3 : g4;
      d = (t == 0) ? g1b : (t == 1) ? g2b : (t == 2) ? g3b : g4b;
    }
  }
  const float4 f = ((const float4*)s)[off];
  uint2 o; o.x = pk2(f.x, f.y); o.y = pk2(f.z, f.w);
  ((uint2*)d)[off] = o;
}

// ---------------------------------------------------------------------------
// Fused QKV GEMM (m97 structure, 16x16x32): C[16384,3072] = Xb*[Wq;Wk;Wv]^T.
// Grid (24, 128): sel = bx>>3 (0=Q,1=K,2=V), (bx&7)*128 = col base.
// ---------------------------------------------------------------------------
__global__ void __launch_bounds__(256)
qkv_gemm(const unsigned short* __restrict__ Xb,
         const unsigned short* __restrict__ Wqb, const unsigned short* __restrict__ Wkb,
         const unsigned short* __restrict__ Wvb,
         unsigned short* __restrict__ Q, unsigned short* __restrict__ Kf,
         unsigned short* __restrict__ VT) {
  constexpr int K = 1024;
  __shared__ unsigned short As[128 * 32];
  __shared__ unsigned short Bs[128 * 32];
  const int tid = threadIdx.x;
  const int bx = blockIdx.x;
  const int rowBase = blockIdx.y * 128;
  const int sel = bx >> 3;
  const int colBase = (bx & 7) * 128;
  const unsigned short* Bw = (sel == 0) ? Wqb : ((sel == 1) ? Wkb : Wvb);

  const int lane = tid & 63, wid = tid >> 6;
  const int lq = lane & 15, quad = lane >> 4;
  const int wm = (wid >> 1) * 64, wn = (wid & 1) * 64;

  const int srow = wid * 32 + (lane >> 2);
  const int scol = (lane & 3) * 8;
  const unsigned short* gA = Xb + (size_t)(rowBase + srow) * K + scol;
  const unsigned short* gB = Bw + (size_t)(colBase + srow) * K + scol;
  unsigned short* lA0 = As + wid * 1024;
  unsigned short* lA1 = As + wid * 1024 + 512;
  unsigned short* lB0 = Bs + wid * 1024;
  unsigned short* lB1 = Bs + wid * 1024 + 512;

  f32x4 acc[4][4] = {};
  for (int kt = 0; kt < K / 32; ++kt) {
    __syncthreads();
    gl_lds16(gA + kt * 32, lA0);
    gl_lds16(gA + kt * 32 + 16 * K, lA1);
    gl_lds16(gB + kt * 32, lB0);
    gl_lds16(gB + kt * 32 + 16 * K, lB1);
    __syncthreads();
    bf16x8 af[4], bfr[4];
#pragma unroll
    for (int i = 0; i < 4; ++i)
      af[i] = *(const bf16x8*)(As + (wm + i * 16 + lq) * 32 + quad * 8);
#pragma unroll
    for (int j = 0; j < 4; ++j)
      bfr[j] = *(const bf16x8*)(Bs + (wn + j * 16 + lq) * 32 + quad * 8);
#pragma unroll
    for (int i = 0; i < 4; ++i)
#pragma unroll
      for (int j = 0; j < 4; ++j) acc[i][j] = mfma16(af[i], bfr[j], acc[i][j]);
  }
  // C/D layout: col = lane&15, row = quad*4 + reg  [m89-verified]
  if (sel < 2) {
    unsigned short* C = (sel == 0) ? Q : Kf;
#pragma unroll
    for (int i = 0; i < 4; ++i)
#pragma unroll
      for (int j = 0; j < 4; ++j) {
        const int col = colBase + wn + j * 16 + lq;
#pragma unroll
        for (int r = 0; r < 4; ++r) {
          const int row = rowBase + wm + i * 16 + quad * 4 + r;
          C[(size_t)row * 1024 + col] = f2bf(acc[i][j][r]);
        }
      }
  } else {
#pragma unroll
    for (int i = 0; i < 4; ++i)
#pragma unroll
      for (int j = 0; j < 4; ++j) {
        const int col = colBase + wn + j * 16 + lq;   // 0..1023
        const int h = col >> 7, dv = col & 127;
        const int row0 = rowBase + wm + i * 16 + quad * 4;
        const int b = row0 >> 13, tl = row0 & 8191;
        ushort4 t4;
        t4.x = f2bf(acc[i][j][0]); t4.y = f2bf(acc[i][j][1]);
        t4.z = f2bf(acc[i][j][2]); t4.w = f2bf(acc[i][j][3]);
        *(ushort4*)(VT + (((size_t)(b * 8 + h) * 128 + dv) << 13) + tl) = t4;
      }
  }
}

// ---------------------------------------------------------------------------
// Final GEMM (m97 structure, 16x16x32): out[16384,1024] f32 = O * Wo^T.
// ---------------------------------------------------------------------------
__global__ void __launch_bounds__(256)
out_gemm(const unsigned short* __restrict__ A, const unsigned short* __restrict__ Bw,
         float* __restrict__ C) {
  constexpr int K = 1024;
  __shared__ unsigned short As[128 * 32];
  __shared__ unsigned short Bs[128 * 32];
  const int tid = threadIdx.x;
  const int rowBase = blockIdx.y * 128;
  const int colBase = blockIdx.x * 128;
  const int lane = tid & 63, wid = tid >> 6;
  const int lq = lane & 15, quad = lane >> 4;
  const int wm = (wid >> 1) * 64, wn = (wid & 1) * 64;

  const int srow = wid * 32 + (lane >> 2);
  const int scol = (lane & 3) * 8;
  const unsigned short* gA = A + (size_t)(rowBase + srow) * K + scol;
  const unsigned short* gB = Bw + (size_t)(colBase + srow) * K + scol;
  unsigned short* lA0 = As + wid * 1024;
  unsigned short* lA1 = As + wid * 1024 + 512;
  unsigned short* lB0 = Bs + wid * 1024;
  unsigned short* lB1 = Bs + wid * 1024 + 512;

  f32x4 acc[4][4] = {};
  for (int kt = 0; kt < K / 32; ++kt) {
    __syncthreads();
    gl_lds16(gA + kt * 32, lA0);
    gl_lds16(gA + kt * 32 + 16 * K, lA1);
    gl_lds16(gB + kt * 32, lB0);
    gl_lds16(gB + kt * 32 + 16 * K, lB1);
    __syncthreads();
    bf16x8 af[4], bfr[4];
#pragma unroll
    for (int i = 0; i < 4; ++i)
      af[i] = *(const bf16x8*)(As + (wm + i * 16 + lq) * 32 + quad * 8);
#pragma unroll
    for (int j = 0; j < 4; ++j)
      bfr[j] = *(const bf16x8*)(Bs + (wn + j * 16 + lq) * 32 + quad * 8);
#pragma unroll
    for (int i = 0; i < 4; ++i)
#pragma unroll
      for (int j = 0; j < 4; ++j) acc[i][j] = mfma16(af[i], bfr[j], acc[i][j]);
  }
#pragma unroll
  for (int i = 0; i < 4; ++i)
#pragma unroll
    for (int j = 0; j < 4; ++j) {
      const int col = colBase + wn + j * 16 + lq;
#pragma unroll
      for (int r = 0; r < 4; ++r) {
        const int row = rowBase + wm + i * 16 + quad * 4 + r;
        C[(size_t)row * 1024 + col] = acc[i][j][r];
      }
    }
}

// ---------------------------------------------------------------------------
// Feature map (per head): buf = (buf@w1^T + b1) * (buf@w2^T + b2) * scale,
// in place. Grid (BT/256, 8, 2). 4 token-tiles/block, W register-hoisted.
// ---------------------------------------------------------------------------
__global__ void __launch_bounds__(256)
fm_kernel(unsigned short* __restrict__ Qb, unsigned short* __restrict__ Kb,
          const unsigned short* __restrict__ fq1b, const unsigned short* __restrict__ fq2b,
          const unsigned short* __restrict__ fk1b, const unsigned short* __restrict__ fk2b,
          const float* __restrict__ fqb1, const float* __restrict__ fqb2,
          const float* __restrict__ fkb1, const float* __restrict__ fkb2) {
  __shared__ unsigned short Aq[64 * 136];
  const int z = blockIdx.z;
  unsigned short* buf = z ? Kb : Qb;
  const unsigned short* w1b = z ? fk1b : fq1b;
  const unsigned short* w2b = z ? fk2b : fq2b;
  const float* b1 = z ? fkb1 : fqb1;
  const float* b2 = z ? fkb2 : fqb2;
  const float scale = z ? 1.0f : 0.08838834764831843f;

  const int tid = threadIdx.x;
  const int t0 = blockIdx.x * 256;
  const int h = blockIdx.y, hc = h * 128;
  const int lane = tid & 63, wid = tid >> 6, lq = lane & 15, quad = lane >> 4;
  const int wn = wid * 32;

  bf16x8 w1f[4][2], w2f[4][2];
#pragma unroll
  for (int ks = 0; ks < 4; ++ks)
#pragma unroll
    for (int j = 0; j < 2; ++j) {
      const int nr = wn + j * 16 + lq;
      w1f[ks][j] = *(const bf16x8*)(w1b + nr * 128 + ks * 32 + quad * 8);
      w2f[ks][j] = *(const bf16x8*)(w2b + nr * 128 + ks * 32 + quad * 8);
    }
  const float bb1[2] = { b1[wn + lq], b1[wn + 16 + lq] };
  const float bb2[2] = { b2[wn + lq], b2[wn + 16 + lq] };

  for (int tt = 0; tt < 4; ++tt) {
    const int tb = t0 + tt * 64;
#pragma unroll
    for (int it = 0; it < 4; ++it) {
      const int p = tid + it * 256;
      const int row = p >> 4, c8 = (p & 15) * 8;
      *(uint4*)(Aq + row * 136 + c8) =
          *(const uint4*)(buf + (size_t)(tb + row) * 1024 + hc + c8);
    }
    __syncthreads();
    f32x4 a1[4][2] = {}, a2[4][2] = {};
#pragma unroll
    for (int ks = 0; ks < 4; ++ks) {
      bf16x8 af[4];
#pragma unroll
      for (int i = 0; i < 4; ++i)
        af[i] = *(const bf16x8*)(Aq + (i * 16 + lq) * 136 + ks * 32 + quad * 8);
#pragma unroll
      for (int j = 0; j < 2; ++j)
#pragma unroll
        for (int i = 0; i < 4; ++i) {
          a1[i][j] = mfma16(af[i], w1f[ks][j], a1[i][j]);
          a2[i][j] = mfma16(af[i], w2f[ks][j], a2[i][j]);
        }
    }
    __syncthreads();
#pragma unroll
    for (int j = 0; j < 2; ++j) {
      const int col = wn + j * 16 + lq;
#pragma unroll
      for (int i = 0; i < 4; ++i)
#pragma unroll
        for (int r = 0; r < 4; ++r) {
          const float v = (a1[i][j][r] + bb1[j]) * (a2[i][j][r] + bb2[j]) * scale;
          buf[(size_t)(tb + i * 16 + quad * 4 + r) * 1024 + hc + col] = f2bf(v);
        }
    }
  }
}

// ---------------------------------------------------------------------------
// Per-chunk KV outer product: KV[bh,n][dv][dk] = sum_c V[c][dv] * K[c][dk].
// ---------------------------------------------------------------------------
__global__ void __launch_bounds__(256)
kv_kernel(const unsigned short* __restrict__ Kf, const unsigned short* __restrict__ VT,
          unsigned short* __restrict__ KV) {
  __shared__ unsigned short Kt[128 * 72];
  __shared__ unsigned short Vt[128 * 72];
  const int tid = threadIdx.x;
  const int n = blockIdx.x, bh = blockIdx.y;
  const int b = bh >> 3, h = bh & 7;
  const int t0g = b * 8192 + n * 64;
  const int tl0 = n * 64;
#pragma unroll
  for (int it = 0; it < 4; ++it) {
    const int p = tid + it * 256;
    const int d = p >> 3, c8 = (p & 7) * 8;
    *(uint4*)(Vt + d * 72 + c8) =
        *(const uint4*)(VT + (((size_t)bh * 128 + d) << 13) + tl0 + c8);
    const int tok = p >> 4, c8k = (p & 15) * 8;
    const unsigned short* src = Kf + (size_t)(t0g + tok) * 1024 + h * 128 + c8k;
    ushort4 k0 = *(const ushort4*)(src);
    ushort4 k1 = *(const ushort4*)(src + 4);
    Kt[(c8k + 0) * 72 + tok] = k0.x; Kt[(c8k + 1) * 72 + tok] = k0.y;
    Kt[(c8k + 2) * 72 + tok] = k0.z; Kt[(c8k + 3) * 72 + tok] = k0.w;
    Kt[(c8k + 4) * 72 + tok] = k1.x; Kt[(c8k + 5) * 72 + tok] = k1.y;
    Kt[(c8k + 6) * 72 + tok] = k1.z; Kt[(c8k + 7) * 72 + tok] = k1.w;
  }
  __syncthreads();
  const int lane = tid & 63, wid = tid >> 6, lq = lane & 15, quad = lane >> 4;
  const int wm = (wid >> 1) * 64, wn = (wid & 1) * 64;
  f32x4 acc[4][4] = {};
#pragma unroll
  for (int ks = 0; ks < 2; ++ks) {
    bf16x8 af[4], bfr[4];
#pragma unroll
    for (int i = 0; i < 4; ++i)
      af[i] = *(const bf16x8*)(Vt + (wm + i * 16 + lq) * 72 + ks * 32 + quad * 8);
#pragma unroll
    for (int j = 0; j < 4; ++j)
      bfr[j] = *(const bf16x8*)(Kt + (wn + j * 16 + lq) * 72 + ks * 32 + quad * 8);
#pragma unroll
    for (int i = 0; i < 4; ++i)
#pragma unroll
      for (int j = 0; j < 4; ++j) acc[i][j] = mfma16(af[i], bfr[j], acc[i][j]);
  }
  const size_t base = ((size_t)bh * 128 + n) * 16384;
#pragma unroll
  for (int i = 0; i < 4; ++i)
#pragma unroll
    for (int j = 0; j < 4; ++j)
#pragma unroll
      for (int r = 0; r < 4; ++r)
        KV[base + (size_t)(wm + i * 16 + quad * 4 + r) * 128 + wn + j * 16 + lq] =
            f2bf(acc[i][j][r]);
}

// ---------------------------------------------------------------------------
// Exclusive prefix sum over 128 chunks, in place. R9: uint2 per thread
// (4 bf16 columns), 4x fewer load/store instructions. Grid 256 x 256.
// ---------------------------------------------------------------------------
__global__ void __launch_bounds__(256)
cumsum_kernel(unsigned short* __restrict__ KV) {
  const int idx = blockIdx.x * 256 + threadIdx.x;  // 0..65535
  const int bh = idx >> 12, e4 = idx & 4095;
  unsigned int* p = (unsigned int*)(KV + (size_t)bh * (128 * 16384)) + e4 * 2;
  float r0 = 0.f, r1 = 0.f, r2 = 0.f, r3 = 0.f;
  for (int n = 0; n < 128; ++n) {
    const unsigned int u0 = p[0], u1 = p[1];
    const float x0 = bf2f(u0 & 0xFFFFu), x1 = bf2f(u0 >> 16);
    const float x2 = bf2f(u1 & 0xFFFFu), x3 = bf2f(u1 >> 16);
    p[0] = pk2(r0, r1); p[1] = pk2(r2, r3);  // exclusive
    r0 += x0; r1 += x1; r2 += x2; r3 += x3;
    p += 8192;  // next chunk (16384 ush)
  }
}

// ---------------------------------------------------------------------------
// Attention chunk kernel: o = tril(q k^T) v + q S, fused RMSNorm, per (b,h,n).
// R9 layout (54,272 B -> 3 blocks/CU):
//   SQ 64x136 | R2 9216 ush: k(136) -> AL(72) -> S2(72) | R3 9216: VT(72) -> S1(72)
//   OL (f32 64x132) overlays; RED/SCL after OL. O aliases Q (reads ph1 only).
// ---------------------------------------------------------------------------
__global__ void __launch_bounds__(256)
attn_kernel(const unsigned short* __restrict__ Q, const unsigned short* __restrict__ Kf,
            const unsigned short* __restrict__ VT, const unsigned short* __restrict__ S,
            const float* __restrict__ rmsw, unsigned short* __restrict__ O) {
  __shared__ uint4 smem4[3392];  // 54,272 B
  unsigned short* sm = (unsigned short*)smem4;
  unsigned short* SQ = sm;            // stride 136, 64 rows
  unsigned short* R2 = sm + 8704;     // 9216 ush
  unsigned short* R3 = sm + 17920;    // 9216 ush
  float* OL = (float*)sm;             // stride 132, 64 rows (33,792 B)
  float* RED = (float*)(sm + 16896);  // 256 f32
  float* SCL = RED + 256;             // 64 f32

  const int tid = threadIdx.x;
  const int n = blockIdx.x, bh = blockIdx.y;
  const int b = bh >> 3, h = bh & 7;
  const int t0g = b * 8192 + n * 64;
  const int tl0 = n * 64;
  const int lane = tid & 63, wid = tid >> 6, lq = lane & 15, quad = lane >> 4;

  // Phase 1: stage q -> SQ, k -> R2 (stride 136), V^T -> R3 (stride 72).
#pragma unroll
  for (int it = 0; it < 4; ++it) {
    const int p = tid + it * 256;
    const int row = p >> 4, c8 = (p & 15) * 8;
    *(uint4*)(SQ + row * 136 + c8) =
        *(const uint4*)(Q + (size_t)(t0g + row) * 1024 + h * 128 + c8);
    *(uint4*)(R2 + row * 136 + c8) =
        *(const uint4*)(Kf + (size_t)(t0g + row) * 1024 + h * 128 + c8);
    const int d = p >> 3, c8b = (p & 7) * 8;
    *(uint4*)(R3 + d * 72 + c8b) =
        *(const uint4*)(VT + (((size_t)bh * 128 + d) << 13) + tl0 + c8b);
  }
  __syncthreads();

  // Phase 2: A = q k^T (wave w owns k-positions w*16..+15).
  f32x4 aa[4] = {};
#pragma unroll
  for (int ks = 0; ks < 4; ++ks) {
    bf16x8 kf = *(const bf16x8*)(R2 + (wid * 16 + lq) * 136 + ks * 32 + quad * 8);
#pragma unroll
    for (int i = 0; i < 4; ++i) {
      bf16x8 qf = *(const bf16x8*)(SQ + (i * 16 + lq) * 136 + ks * 32 + quad * 8);
      aa[i] = mfma16(qf, kf, aa[i]);
    }
  }
  __syncthreads();  // all k reads done before AL overwrites R2
#pragma unroll
  for (int i = 0; i < 4; ++i)
#pragma unroll
    for (int r = 0; r < 4; ++r) {
      const int qp = i * 16 + quad * 4 + r, kp = wid * 16 + lq;
      R2[qp * 72 + kp] = f2bf(kp <= qp ? aa[i][r] : 0.f);  // AL
    }
  __syncthreads();

  // Phase 3: o += A_masked * V (A from R2, V from R3). Wave owns dv wid*32..+31.
  f32x4 oa[4][2] = {};
#pragma unroll
  for (int ks = 0; ks < 2; ++ks) {
    bf16x8 bv[2];
#pragma unroll
    for (int j = 0; j < 2; ++j)
      bv[j] = *(const bf16x8*)(R3 + (wid * 32 + j * 16 + lq) * 72 + ks * 32 + quad * 8);
#pragma unroll
    for (int i = 0; i < 4; ++i) {
      bf16x8 af = *(const bf16x8*)(R2 + (i * 16 + lq) * 72 + ks * 32 + quad * 8);
#pragma unroll
      for (int j = 0; j < 2; ++j) oa[i][j] = mfma16(af, bv[j], oa[i][j]);
    }
  }
  __syncthreads();  // AL + VT reads done

  // Phase 4: stage full S: dk 0..63 -> R3, dk 64..127 -> R2 (stride 72).
  const size_t sbase = ((size_t)bh * 128 + n) * 16384;
#pragma unroll
  for (int it = 0; it < 4; ++it) {
    const int p = tid + it * 256;
    const int dv = p >> 3, c8 = (p & 7) * 8;
    *(uint4*)(R3 + dv * 72 + c8) = *(const uint4*)(S + sbase + (size_t)dv * 128 + c8);
    *(uint4*)(R2 + dv * 72 + c8) =
        *(const uint4*)(S + sbase + (size_t)dv * 128 + 64 + c8);
  }
  __syncthreads();

  // Phase 5: o += q * S (all 4 k-slices).
#pragma unroll
  for (int ks = 0; ks < 4; ++ks) {
    const unsigned short* Sb = (ks < 2) ? R3 : R2;
    const int co = (ks & 1) * 32;
    bf16x8 sf[2];
#pragma unroll
    for (int j = 0; j < 2; ++j)
      sf[j] = *(const bf16x8*)(Sb + (wid * 32 + j * 16 + lq) * 72 + co + quad * 8);
#pragma unroll
    for (int i = 0; i < 4; ++i) {
      bf16x8 qf = *(const bf16x8*)(SQ + (i * 16 + lq) * 136 + ks * 32 + quad * 8);
#pragma unroll
      for (int j = 0; j < 2; ++j) oa[i][j] = mfma16(qf, sf[j], oa[i][j]);
    }
  }
  __syncthreads();

  // Phase 6: spill o (fp32) to LDS for cross-wave RMSNorm.
#pragma unroll
  for (int i = 0; i < 4; ++i)
#pragma unroll
    for (int j = 0; j < 2; ++j)
#pragma unroll
      for (int r = 0; r < 4; ++r)
        OL[(i * 16 + quad * 4 + r) * 132 + wid * 32 + j * 16 + lq] = oa[i][j][r];
  __syncthreads();

  // Phase 7: row sum of squares (4 partials per row), then scales.
  {
    const int r = tid >> 2, part = tid & 3;
    const float* pr = OL + r * 132 + part * 32;
    float s = 0.f;
#pragma unroll
    for (int c = 0; c < 32; ++c) { const float v = pr[c]; s += v * v; }
    RED[r * 4 + part] = s;
  }
  __syncthreads();
  if (tid < 64) {
    const float ms = (RED[tid * 4] + RED[tid * 4 + 1] + RED[tid * 4 + 2] + RED[tid * 4 + 3]) *
                     (1.f / 128.f);
    SCL[tid] = rsqrtf(ms + 1e-5f);
  }
  __syncthreads();

  // Phase 8: normalize * rms_w (f32), pack bf16, coalesced 16B stores.
#pragma unroll
  for (int it = 0; it < 4; ++it) {
    const int r = (tid >> 4) + it * 16;
    const int c8 = (tid & 15) * 8;
    const float sc = SCL[r];
    unsigned short us[8];
#pragma unroll
    for (int e = 0; e < 8; ++e)
      us[e] = f2bf(OL[r * 132 + c8 + e] * sc * rmsw[c8 + e]);
    uint4 pk;
    pk.x = (unsigned int)us[0] | ((unsigned int)us[1] << 16);
    pk.y = (unsigned int)us[2] | ((unsigned int)us[3] << 16);
    pk.z = (unsigned int)us[4] | ((unsigned int)us[5] << 16);
    pk.w = (unsigned int)us[6] | ((unsigned int)us[7] << 16);
    *(uint4*)(O + (size_t)(t0g + r) * 1024 + h * 128 + c8) = pk;
  }
}

// ---------------------------------------------------------------------------
extern "C" void kernel_launch(void* const* d_in, const int* in_sizes, int n_in,
                              void* d_out, int out_size, void* d_ws, size_t ws_size,
                              hipStream_t stream) {
  const float* X    = (const float*)d_in[0];
  const float* Wq   = (const float*)d_in[1];
  const float* Wk   = (const float*)d_in[2];
  const float* Wv   = (const float*)d_in[3];
  const float* fq1  = (const float*)d_in[4];
  const float* fqb1 = (const float*)d_in[5];
  const float* fq2  = (const float*)d_in[6];
  const float* fqb2 = (const float*)d_in[7];
  const float* fk1  = (const float*)d_in[8];
  const float* fkb1 = (const float*)d_in[9];
  const float* fk2  = (const float*)d_in[10];
  const float* fkb2 = (const float*)d_in[11];
  const float* rmsw = (const float*)d_in[12];
  const float* Wo   = (const float*)d_in[13];

  const size_t MB = 1u << 20;
  char* ws = (char*)d_ws;
  unsigned short* Q    = (unsigned short*)(ws);             // 32 MB (O in-place)
  unsigned short* Kf   = (unsigned short*)(ws + 32 * MB);   // 32 MB
  unsigned short* VT   = (unsigned short*)(ws + 64 * MB);   // 32 MB [b,h,dv,t]
  unsigned short* KV   = (unsigned short*)(ws + 96 * MB);   // 64 MB chunk states
  unsigned short* Xb   = KV;                                // 32 MB, dead after QKV
  unsigned short* Wqb  = (unsigned short*)(ws + 160 * MB);
  unsigned short* Wkb  = (unsigned short*)(ws + 162 * MB);
  unsigned short* Wvb  = (unsigned short*)(ws + 164 * MB);
  unsigned short* Wob  = (unsigned short*)(ws + 166 * MB);
  unsigned short* fq1b = (unsigned short*)(ws + 168 * MB);
  unsigned short* fq2b = fq1b + 16384;
  unsigned short* fk1b = fq1b + 32768;
  unsigned short* fk2b = fq1b + 49152;
  unsigned short* O    = Q;

  cvt_all<<<20544, 256, 0, stream>>>(X, Wq, Wk, Wv, Wo, fq1, fq2, fk1, fk2,
                                     Xb, Wqb, Wkb, Wvb, Wob,
                                     fq1b, fq2b, fk1b, fk2b);
  qkv_gemm<<<dim3(24, 128), 256, 0, stream>>>(Xb, Wqb, Wkb, Wvb, Q, Kf, VT);
  fm_kernel<<<dim3(64, 8, 2), 256, 0, stream>>>(Q, Kf, fq1b, fq2b, fk1b, fk2b,
                                                fqb1, fqb2, fkb1, fkb2);
  kv_kernel<<<dim3(128, 16), 256, 0, stream>>>(Kf, VT, KV);
  cumsum_kernel<<<256, 256, 0, stream>>>(KV);
  attn_kernel<<<dim3(128, 16), 256, 0, stream>>>(Q, Kf, VT, KV, rmsw, O);
  out_gemm<<<dim3(8, 128), 256, 0, stream>>>(O, Wob, (float*)d_out);
}